// Round 1
// baseline (3134.118 us; speedup 1.0000x reference)
//
#include <hip/hip_runtime.h>

// ConditionalCNF: RK4 (20 steps) of scalar-z CNF with 3-layer tanh MLP
// (din=9, H=32) + exact divergence. One thread per sample; weights in LDS
// (uniform broadcast reads); per-sample c1/h1/d1 in registers.
//
// B = 524288, C = 8, H = 32. Purely VALU-bound (~1.9e11 fp32 FLOP, ~23 MB
// HBM traffic). No fp32 MFMA on CDNA4 -> vector ALU path.

constexpr int H = 32;
constexpr int C = 8;
constexpr int DIN = 9;      // 1 + C
constexpr int NSTEPS = 20;

__device__ __forceinline__ float fast_tanh(float x) {
    // tanh(x) = 1 - 2/(exp(2x)+1); exact identity, ~1e-6 abs error with
    // v_exp_f32 + v_rcp_f32. Saturates correctly: exp->inf => 1, exp->0 => -1.
    float e = __expf(2.0f * x);             // v_mul + v_exp_f32
    float r = __builtin_amdgcn_rcpf(e + 1.0f);  // v_add + v_rcp_f32
    return fmaf(-2.0f, r, 1.0f);
}

__global__ __launch_bounds__(256) void cnf_kernel(
    const float* __restrict__ Tin, const float* __restrict__ cond,
    const float* __restrict__ W1, const float* __restrict__ b1,
    const float* __restrict__ W2, const float* __restrict__ b2,
    const float* __restrict__ W3, const float* __restrict__ b3,
    float* __restrict__ out, int B)
{
    __shared__ __align__(16) float W2s[H * H];  // [j][k] row-major
    __shared__ float b2s[H];
    __shared__ float w3s[H];
    __shared__ float w1zs[H];       // W1[:,0]
    __shared__ float W1cs[H * C];   // W1[:,1..8], [j][k]
    __shared__ float b1s[H];
    __shared__ float b3s;

    const int t = threadIdx.x;
    for (int i = t; i < H * H; i += blockDim.x) W2s[i] = W2[i];
    if (t < H) {
        b2s[t]  = b2[t];
        w3s[t]  = W3[t];
        w1zs[t] = W1[t * DIN];
        b1s[t]  = b1[t];
    }
    if (t == 0) b3s = b3[0];
    for (int i = t; i < H * C; i += blockDim.x) {
        int j = i / C, k = i % C;
        W1cs[i] = W1[j * DIN + 1 + k];
    }
    __syncthreads();

    const int gid = blockIdx.x * blockDim.x + t;
    if (gid >= B) return;

    // ---- per-sample setup ----
    float cd[C];
    {
        const float4* c4 = reinterpret_cast<const float4*>(cond + (size_t)gid * C);
        float4 ca = c4[0], cb = c4[1];
        cd[0] = ca.x; cd[1] = ca.y; cd[2] = ca.z; cd[3] = ca.w;
        cd[4] = cb.x; cd[5] = cb.y; cd[6] = cb.z; cd[7] = cb.w;
    }

    // c1[j] = b1[j] + sum_k cond[k] * W1[j][k+1]  (cond is constant over the
    // whole integration -> layer 1 per eval reduces to one FMA per unit)
    float c1[H];
#pragma unroll
    for (int j = 0; j < H; ++j) {
        float s = b1s[j];
#pragma unroll
        for (int k = 0; k < C; ++k) s = fmaf(cd[k], W1cs[j * C + k], s);
        c1[j] = s;
    }

    float z = Tin[gid];
    float l = 0.0f;
    const float dt = (1.0f - 0.0f) / (float)NSTEPS;
    const float b3v = b3s;

    for (int step = 0; step < NSTEPS; ++step) {
        float kz_prev = 0.0f;
        float accz = 0.0f, accl = 0.0f;
#pragma unroll 1
        for (int s4 = 0; s4 < 4; ++s4) {
            // stage coefficients (branchless; s4 is wave-uniform)
            const float a = (s4 == 0) ? 0.0f : ((s4 == 3) ? dt : 0.5f * dt);
            const float w = ((s4 == 0) | (s4 == 3)) ? (dt / 6.0f) : (dt / 3.0f);
            const float zin = fmaf(a, kz_prev, z);

            // ---- dynamics eval: fz = dz/dt, fl = divergence ----
            float h1v[H], d1v[H];
#pragma unroll
            for (int j = 0; j < H; ++j) {
                const float wz = w1zs[j];
                const float h = fast_tanh(fmaf(zin, wz, c1[j]));
                h1v[j] = h;
                d1v[j] = (1.0f - h * h) * wz;
            }

            float fz = b3v, fl = 0.0f;
#pragma unroll 4
            for (int j = 0; j < H; ++j) {
                float s = b2s[j], sd = 0.0f;
                const float4* W2row = reinterpret_cast<const float4*>(&W2s[j * H]);
#pragma unroll
                for (int kk = 0; kk < H / 4; ++kk) {
                    const float4 w4 = W2row[kk];
                    s  = fmaf(h1v[4 * kk + 0], w4.x, s);
                    sd = fmaf(d1v[4 * kk + 0], w4.x, sd);
                    s  = fmaf(h1v[4 * kk + 1], w4.y, s);
                    sd = fmaf(d1v[4 * kk + 1], w4.y, sd);
                    s  = fmaf(h1v[4 * kk + 2], w4.z, s);
                    sd = fmaf(d1v[4 * kk + 2], w4.z, sd);
                    s  = fmaf(h1v[4 * kk + 3], w4.w, s);
                    sd = fmaf(d1v[4 * kk + 3], w4.w, sd);
                }
                const float h2 = fast_tanh(s);
                const float dd = (1.0f - h2 * h2) * sd;
                const float w3 = w3s[j];
                fz = fmaf(h2, w3, fz);
                fl = fmaf(dd, w3, fl);
            }

            kz_prev = fz;
            accz = fmaf(w, fz, accz);
            accl = fmaf(w, fl, accl);
        }
        z += accz;
        l += accl;
    }

    out[gid] = z;
    out[(size_t)B + gid] = l;
}

extern "C" void kernel_launch(void* const* d_in, const int* in_sizes, int n_in,
                              void* d_out, int out_size, void* d_ws, size_t ws_size,
                              hipStream_t stream) {
    const float* T    = (const float*)d_in[0];
    const float* cond = (const float*)d_in[1];
    const float* W1   = (const float*)d_in[2];
    const float* b1   = (const float*)d_in[3];
    const float* W2   = (const float*)d_in[4];
    const float* b2   = (const float*)d_in[5];
    const float* W3   = (const float*)d_in[6];
    const float* b3   = (const float*)d_in[7];
    float* out = (float*)d_out;

    const int B = in_sizes[0];
    const int block = 256;
    const int grid = (B + block - 1) / block;
    cnf_kernel<<<grid, block, 0, stream>>>(T, cond, W1, b1, W2, b2, W3, b3, out, B);
}

// Round 2
// 1267.557 us; speedup vs baseline: 2.4726x; 2.4726x over previous
//
#include <hip/hip_runtime.h>

// ConditionalCNF via MFMA: per wave, per eval, the two H=32 matvecs over 64
// samples form [64x32]@[32x32] twice -> 16x16x32 bf16 MFMAs (W2 split into
// hi+lo bf16 for fp32-grade weight accuracy; 32 MFMAs/eval total).
//
// Lane layouts (all m89/m118/m120-verified gfx950 mappings):
//   A-frag:  A[m=lane&15][k=(lane>>4)*8+j]   -> lane computes h1/d1 for
//            sample 16b+(lane&15), k-chunk (lane>>4)*8.. directly (no LDS).
//   B-frag:  B[k=(lane>>4)*8+j][n=lane&15]   -> lane holds W2 row (lane&15)+16t,
//            8 consecutive k.
//   C/D:     col=lane&15 (unit n), row=(lane>>4)*4+reg (sample-within-block).
// Owner-lane layout for per-sample scalars: lane o owns sample
//   s(o) = 16*((o&15)>>2) + 4*(o>>4) + (o&3)  (an involution of b<->q), so the
// post-MFMA 16-lane row reduction lands the result in the owner's own row.

typedef __attribute__((ext_vector_type(8))) short short8;
typedef __attribute__((ext_vector_type(4))) float floatx4;

constexpr int NSTEPS = 20;

struct U128 { unsigned a, b, c, d; };

__device__ __forceinline__ float fast_tanh(float x) {
    float e = __expf(2.0f * x);
    float r = __builtin_amdgcn_rcpf(e + 1.0f);
    return fmaf(-2.0f, r, 1.0f);
}

// pack two f32 -> bf16x2 (round-half-up: +0x8000 then take high halves via v_perm)
__device__ __forceinline__ unsigned pack2bf(float a, float b) {
    unsigned ua = __builtin_bit_cast(unsigned, a) + 0x8000u;
    unsigned ub = __builtin_bit_cast(unsigned, b) + 0x8000u;
    return __builtin_amdgcn_perm(ub, ua, 0x07060302u);
}

__device__ __forceinline__ float bf2f(unsigned bf) {  // bf16 in low 16 bits
    return __builtin_bit_cast(float, bf << 16);
}

template <int CTRL>
__device__ __forceinline__ float dpp_radd(float x) {
    int y = __builtin_amdgcn_update_dpp(0, __builtin_bit_cast(int, x), CTRL, 0xf, 0xf, true);
    return x + __builtin_bit_cast(float, y);
}

// full sum across each 16-lane row: xor1, xor2 (quad_perm), xor7 (half_mirror),
// xor15 (mirror) — every lane in the row ends with the row total.
__device__ __forceinline__ float rowsum16(float x) {
    x = dpp_radd<0xB1>(x);    // quad_perm [1,0,3,2]
    x = dpp_radd<0x4E>(x);    // quad_perm [2,3,0,1]
    x = dpp_radd<0x141>(x);   // row_half_mirror
    x = dpp_radd<0x140>(x);   // row_mirror
    return x;
}

__global__ __launch_bounds__(256) void cnf_mfma(
    const float* __restrict__ Tin, const float* __restrict__ cond,
    const float* __restrict__ W1, const float* __restrict__ b1,
    const float* __restrict__ W2, const float* __restrict__ b2,
    const float* __restrict__ W3, const float* __restrict__ b3,
    float* __restrict__ out, int B)
{
    const int tid   = threadIdx.x;
    const int lane  = tid & 63;
    const int wbase = blockIdx.x * 256 + (tid >> 6) * 64;   // 64 samples/wave

    const int m   = lane & 15;        // A-row (sample-within-block) / D-col (unit)
    const int qk  = lane >> 4;        // k-chunk quad (also D row-quad)
    const int b_o = (lane >> 2) & 3;  // owner decode
    const int r_o = lane & 3;
    const int s_own = 16 * b_o + 4 * qk + r_o;  // local sample owned by this lane

    // bpermute source addresses: block b needs zin of local sample 16b+m,
    // owned by lane 16*(m>>2) + 4*b + (m&3)
    int addrA[4];
#pragma unroll
    for (int b = 0; b < 4; ++b) addrA[b] = ((m >> 2) * 16 + b * 4 + (m & 3)) * 4;

    // ---- B fragments: W2 hi/lo bf16 split; per-lane column constants ----
    short8 Bhi[2], Blo[2];
    float b2n[2], w3n[2];
#pragma unroll
    for (int t = 0; t < 2; ++t) {
        const int u = m + 16 * t;
        const float* w2r = W2 + u * 32 + qk * 8;
        unsigned hu[4], lu[4];
#pragma unroll
        for (int p = 0; p < 4; ++p) {
            const float w0 = w2r[2 * p], w1v = w2r[2 * p + 1];
            const unsigned h0 = (__builtin_bit_cast(unsigned, w0) + 0x8000u) >> 16;
            const unsigned h1 = (__builtin_bit_cast(unsigned, w1v) + 0x8000u) >> 16;
            hu[p] = h0 | (h1 << 16);
            lu[p] = pack2bf(w0 - bf2f(h0), w1v - bf2f(h1));
        }
        Bhi[t] = __builtin_bit_cast(short8, U128{hu[0], hu[1], hu[2], hu[3]});
        Blo[t] = __builtin_bit_cast(short8, U128{lu[0], lu[1], lu[2], lu[3]});
        b2n[t] = b2[u];
        w3n[t] = W3[u];
    }

    // ---- W1 z-column for this lane's k-chunk ----
    float w1zk[8];
#pragma unroll
    for (int j = 0; j < 8; ++j) w1zk[j] = W1[(qk * 8 + j) * 9];

    // ---- c1A[b][j] = b1[k] + cond[s].W1[k][1:9]  (cond constant over ODE) ----
    float c1A[4][8];
#pragma unroll
    for (int b = 0; b < 4; ++b) {
        int s = wbase + 16 * b + m;
        if (s > B - 1) s = B - 1;
        const float4* c4 = reinterpret_cast<const float4*>(cond + (size_t)s * 8);
        const float4 ca = c4[0], cb = c4[1];
        const float cd[8] = {ca.x, ca.y, ca.z, ca.w, cb.x, cb.y, cb.z, cb.w};
#pragma unroll
        for (int j = 0; j < 8; ++j) {
            const int k = qk * 8 + j;
            float acc = b1[k];
#pragma unroll
            for (int jj = 0; jj < 8; ++jj) acc = fmaf(cd[jj], W1[k * 9 + 1 + jj], acc);
            c1A[b][j] = acc;
        }
    }

    const float b3v = b3[0];
    const int sg = wbase + s_own;
    float z = Tin[sg < B ? sg : B - 1];
    float dlog = 0.0f;
    const float dt = 1.0f / (float)NSTEPS;

    for (int step = 0; step < NSTEPS; ++step) {
        float kz = 0.0f, accz = 0.0f, accl = 0.0f;
#pragma unroll 1
        for (int s4 = 0; s4 < 4; ++s4) {
            const float a = (s4 == 0) ? 0.0f : ((s4 == 3) ? dt : 0.5f * dt);
            const float w = ((s4 == 0) | (s4 == 3)) ? (dt * (1.0f / 6.0f))
                                                    : (dt * (1.0f / 3.0f));
            const int zi = __builtin_bit_cast(int, fmaf(a, kz, z));
            float selx = 0.0f, sely = 0.0f;

#pragma unroll
            for (int b = 0; b < 4; ++b) {
                const float zin = __builtin_bit_cast(
                    float, __builtin_amdgcn_ds_bpermute(addrA[b], zi));

                // A fragments: h1 and d1 for sample 16b+m, k = qk*8 + j
                unsigned ahp[4], adp[4];
#pragma unroll
                for (int p = 0; p < 4; ++p) {
                    const float x0 = fmaf(zin, w1zk[2 * p],     c1A[b][2 * p]);
                    const float x1 = fmaf(zin, w1zk[2 * p + 1], c1A[b][2 * p + 1]);
                    const float h0 = fast_tanh(x0);
                    const float h1v = fast_tanh(x1);
                    const float d0  = fmaf(-h0, h0, 1.0f) * w1zk[2 * p];
                    const float d1v = fmaf(-h1v, h1v, 1.0f) * w1zk[2 * p + 1];
                    ahp[p] = pack2bf(h0, h1v);
                    adp[p] = pack2bf(d0, d1v);
                }
                const short8 Ah = __builtin_bit_cast(short8, U128{ahp[0], ahp[1], ahp[2], ahp[3]});
                const short8 Ad = __builtin_bit_cast(short8, U128{adp[0], adp[1], adp[2], adp[3]});
                const floatx4 zero = {0.0f, 0.0f, 0.0f, 0.0f};

                floatx4 Dh0 = __builtin_amdgcn_mfma_f32_16x16x32_bf16(Ah, Blo[0], zero, 0, 0, 0);
                Dh0         = __builtin_amdgcn_mfma_f32_16x16x32_bf16(Ah, Bhi[0], Dh0,  0, 0, 0);
                floatx4 Dh1 = __builtin_amdgcn_mfma_f32_16x16x32_bf16(Ah, Blo[1], zero, 0, 0, 0);
                Dh1         = __builtin_amdgcn_mfma_f32_16x16x32_bf16(Ah, Bhi[1], Dh1,  0, 0, 0);
                floatx4 Dd0 = __builtin_amdgcn_mfma_f32_16x16x32_bf16(Ad, Blo[0], zero, 0, 0, 0);
                Dd0         = __builtin_amdgcn_mfma_f32_16x16x32_bf16(Ad, Bhi[0], Dd0,  0, 0, 0);
                floatx4 Dd1 = __builtin_amdgcn_mfma_f32_16x16x32_bf16(Ad, Blo[1], zero, 0, 0, 0);
                Dd1         = __builtin_amdgcn_mfma_f32_16x16x32_bf16(Ad, Bhi[1], Dd1,  0, 0, 0);

                // D-processing + 16-lane row reduction + owner select
#pragma unroll
                for (int r = 0; r < 4; ++r) {
                    const float h2a = fast_tanh(Dh0[r] + b2n[0]);
                    const float h2b = fast_tanh(Dh1[r] + b2n[1]);
                    const float va = fmaf(h2b, w3n[1], h2a * w3n[0]);
                    const float dda = fmaf(-h2a, h2a, 1.0f) * Dd0[r];
                    const float ddb = fmaf(-h2b, h2b, 1.0f) * Dd1[r];
                    const float vd = fmaf(ddb, w3n[1], dda * w3n[0]);
                    const float fz = rowsum16(va);
                    const float fl = rowsum16(vd);
                    const bool mine = (b_o == b) & (r_o == r);
                    selx = mine ? fz : selx;
                    sely = mine ? fl : sely;
                }
            }
            kz = selx + b3v;
            accz = fmaf(w, kz, accz);
            accl = fmaf(w, sely, accl);
        }
        z += accz;
        dlog += accl;
    }

    if (sg < B) {
        out[sg] = z;
        out[(size_t)B + sg] = dlog;
    }
}

extern "C" void kernel_launch(void* const* d_in, const int* in_sizes, int n_in,
                              void* d_out, int out_size, void* d_ws, size_t ws_size,
                              hipStream_t stream) {
    const float* T    = (const float*)d_in[0];
    const float* cond = (const float*)d_in[1];
    const float* W1   = (const float*)d_in[2];
    const float* b1   = (const float*)d_in[3];
    const float* W2   = (const float*)d_in[4];
    const float* b2   = (const float*)d_in[5];
    const float* W3   = (const float*)d_in[6];
    const float* b3   = (const float*)d_in[7];
    float* out = (float*)d_out;

    const int B = in_sizes[0];
    const int grid = (B + 255) / 256;   // 256 samples per block (4 waves x 64)
    cnf_mfma<<<grid, 256, 0, stream>>>(T, cond, W1, b1, W2, b2, W3, b3, out, B);
}

// Round 4
// 1057.998 us; speedup vs baseline: 2.9623x; 1.1981x over previous
//
#include <hip/hip_runtime.h>

// ConditionalCNF via MFMA (round 4): round-2 verified structure + scale-folded
// exp2-native tanh + merged butterfly reduction.  NO inline-asm v_pk_* (round-3
// NaN bisect: that was the least-verifiable element), no occupancy clamp.
//
// Verified layouts (round 2 passed, absmax 0.0156):
//   A-frag:  A[m=lane&15][k=(lane>>4)*8+j]
//   B-frag:  B[k=(lane>>4)*8+j][n=lane&15]
//   C/D:     col=lane&15 (unit), row=(lane>>4)*4+reg (sample-within-block)
//   owner lane o: sample 16*((o>>2)&3) + 4*(o>>4) + (o&3)
//
// Scaling (s = 2*log2 e): W1z, c1, W2, b2 pre-scaled by s so every tanh is
// exp2 -> +1 -> rcp -> fma (4 ops).  h-path: Dh = s*preact2 (tanh-ready, bias
// folded into MFMA C operand).  d-path: A_d = s*d1, B = s*W2 => Dd = s^2 *
// (d1@W2^T); compensated via w3/s^2 in the final combine.

typedef __attribute__((ext_vector_type(8))) short short8;
typedef __attribute__((ext_vector_type(4))) float floatx4;

constexpr int NSTEPS = 20;
constexpr float SCL = 2.8853900817779268f;   // 2*log2(e)

struct U128 { unsigned a, b, c, d; };

__device__ __forceinline__ float fexp2(float x) {
#if __has_builtin(__builtin_amdgcn_exp2f)
    return __builtin_amdgcn_exp2f(x);
#else
    return exp2f(x);
#endif
}

// tanh with pre-scaled input xs = 2*log2(e)*x:  tanh(x) = 1 - 2/(exp2(xs)+1).
// Saturates cleanly: exp2->inf => 1; exp2->0 => -1.
__device__ __forceinline__ float tanh_s(float xs) {
    const float e = fexp2(xs);
    const float r = __builtin_amdgcn_rcpf(e + 1.0f);
    return fmaf(-2.0f, r, 1.0f);
}

// pack two f32 -> bf16x2 (round-half-up: +0x8000, take high halves via v_perm)
__device__ __forceinline__ unsigned pack2bf(float a, float b) {
    unsigned ua = __builtin_bit_cast(unsigned, a) + 0x8000u;
    unsigned ub = __builtin_bit_cast(unsigned, b) + 0x8000u;
    return __builtin_amdgcn_perm(ub, ua, 0x07060302u);   // lo16=bf16(a), hi16=bf16(b)
}
__device__ __forceinline__ float bf2f(unsigned bf) {
    return __builtin_bit_cast(float, bf << 16);
}

template <int CTRL>
__device__ __forceinline__ float dpp_radd(float x) {
    int y = __builtin_amdgcn_update_dpp(0, __builtin_bit_cast(int, x), CTRL, 0xf, 0xf, true);
    return x + __builtin_bit_cast(float, y);
}
template <int PAT>
__device__ __forceinline__ float swz_add(float x) {
    int y = __builtin_amdgcn_ds_swizzle(__builtin_bit_cast(int, x), PAT);
    return x + __builtin_bit_cast(float, y);
}

// Sum 4 independent values across each 16-lane row; lane ends holding the full
// row-sum of value index (lane&3).  mo=(lane&1), mt=(lane&2).
__device__ __forceinline__ float reduce4(float v0, float v1, float v2, float v3,
                                         bool mo, bool mt) {
    v0 = dpp_radd<0xB1>(v0);            // + xor1 (quad_perm [1,0,3,2])
    v1 = dpp_radd<0xB1>(v1);
    v2 = dpp_radd<0xB1>(v2);
    v3 = dpp_radd<0xB1>(v3);
    float a01 = mo ? v1 : v0;           // merge by lane bit0
    float a23 = mo ? v3 : v2;
    a01 = dpp_radd<0x4E>(a01);          // + xor2 (quad_perm [2,3,0,1])
    a23 = dpp_radd<0x4E>(a23);
    float a = mt ? a23 : a01;           // merge by lane bit1
    a = swz_add<0x101F>(a);             // + xor4 (ds_swizzle)
    a = swz_add<0x201F>(a);             // + xor8
    return a;
}

__global__ __launch_bounds__(256) void cnf_mfma(
    const float* __restrict__ Tin, const float* __restrict__ cond,
    const float* __restrict__ W1, const float* __restrict__ b1,
    const float* __restrict__ W2, const float* __restrict__ b2,
    const float* __restrict__ W3, const float* __restrict__ b3,
    float* __restrict__ out, int B)
{
    const int tid   = threadIdx.x;
    const int lane  = tid & 63;
    const int wbase = blockIdx.x * 256 + (tid >> 6) * 64;

    const int m   = lane & 15;
    const int qk  = lane >> 4;
    const int b_o = (lane >> 2) & 3;
    const int r_o = lane & 3;
    const int s_own = 16 * b_o + 4 * qk + r_o;

    const bool mo = (lane & 1) != 0;
    const bool mt = (lane & 2) != 0;
    bool bsel[4];
#pragma unroll
    for (int b = 0; b < 4; ++b) bsel[b] = (b_o == b);

    int addrA[4];
#pragma unroll
    for (int b = 0; b < 4; ++b) addrA[b] = ((m >> 2) * 16 + b * 4 + (m & 3)) * 4;

    // ---- B fragments: s*W2, hi/lo bf16 split; per-lane column constants ----
    short8 Bhi[2], Blo[2];
    float w3n[2], w3q[2], cb2[2];
    const float is2 = 1.0f / (SCL * SCL);
#pragma unroll
    for (int t = 0; t < 2; ++t) {
        const int u = m + 16 * t;
        const float* w2r = W2 + u * 32 + qk * 8;
        unsigned hu[4], lu[4];
#pragma unroll
        for (int p = 0; p < 4; ++p) {
            const float w0 = SCL * w2r[2 * p], w1v = SCL * w2r[2 * p + 1];
            const unsigned h0 = (__builtin_bit_cast(unsigned, w0) + 0x8000u) >> 16;
            const unsigned h1 = (__builtin_bit_cast(unsigned, w1v) + 0x8000u) >> 16;
            hu[p] = h0 | (h1 << 16);
            lu[p] = pack2bf(w0 - bf2f(h0), w1v - bf2f(h1));
        }
        Bhi[t] = __builtin_bit_cast(short8, U128{hu[0], hu[1], hu[2], hu[3]});
        Blo[t] = __builtin_bit_cast(short8, U128{lu[0], lu[1], lu[2], lu[3]});
        const float w3v = W3[u];
        w3n[t] = w3v;
        w3q[t] = w3v * is2;
        cb2[t] = SCL * b2[u];
    }

    // ---- layer-1 constants for this lane's k-chunk (pre-scaled by s) ----
    float w1zk[8];
#pragma unroll
    for (int j = 0; j < 8; ++j) w1zk[j] = SCL * W1[(qk * 8 + j) * 9];

    float c1A[4][8];
#pragma unroll
    for (int b = 0; b < 4; ++b) {
        int s = wbase + 16 * b + m;
        if (s > B - 1) s = B - 1;
        const float4* c4 = reinterpret_cast<const float4*>(cond + (size_t)s * 8);
        const float4 ca = c4[0], cb = c4[1];
        const float cd[8] = {ca.x, ca.y, ca.z, ca.w, cb.x, cb.y, cb.z, cb.w};
#pragma unroll
        for (int j = 0; j < 8; ++j) {
            const int k = qk * 8 + j;
            float acc = b1[k];
#pragma unroll
            for (int jj = 0; jj < 8; ++jj) acc = fmaf(cd[jj], W1[k * 9 + 1 + jj], acc);
            c1A[b][j] = SCL * acc;
        }
    }

    const floatx4 cinit0 = {cb2[0], cb2[0], cb2[0], cb2[0]};
    const floatx4 cinit1 = {cb2[1], cb2[1], cb2[1], cb2[1]};
    const floatx4 zero   = {0.0f, 0.0f, 0.0f, 0.0f};

    const float b3v = b3[0];
    const int sg = wbase + s_own;
    float z = Tin[sg < B ? sg : B - 1];
    float dlog = 0.0f;
    const float dt = 1.0f / (float)NSTEPS;

    for (int step = 0; step < NSTEPS; ++step) {
        float kz = 0.0f, accz = 0.0f, accl = 0.0f;
#pragma unroll 1
        for (int s4 = 0; s4 < 4; ++s4) {
            const float a = (s4 == 0) ? 0.0f : ((s4 == 3) ? dt : 0.5f * dt);
            const float w = ((s4 == 0) | (s4 == 3)) ? (dt * (1.0f / 6.0f))
                                                    : (dt * (1.0f / 3.0f));
            const int zi = __builtin_bit_cast(int, fmaf(a, kz, z));
            float selx = 0.0f, sely = 0.0f;

#pragma unroll
            for (int b = 0; b < 4; ++b) {
                const float zin = __builtin_bit_cast(
                    float, __builtin_amdgcn_ds_bpermute(addrA[b], zi));

                // ---- A-prep: h1 (bf16) and s*d1 (bf16) ----
                unsigned ahp[4], adp[4];
#pragma unroll
                for (int p = 0; p < 4; ++p) {
                    const float x0 = fmaf(zin, w1zk[2 * p],     c1A[b][2 * p]);
                    const float x1 = fmaf(zin, w1zk[2 * p + 1], c1A[b][2 * p + 1]);
                    const float h0 = tanh_s(x0);
                    const float h1v = tanh_s(x1);
                    ahp[p] = pack2bf(h0, h1v);
                    const float d0  = fmaf(-h0, h0, 1.0f) * w1zk[2 * p];
                    const float d1v = fmaf(-h1v, h1v, 1.0f) * w1zk[2 * p + 1];
                    adp[p] = pack2bf(d0, d1v);
                }
                const short8 Ah = __builtin_bit_cast(short8, U128{ahp[0], ahp[1], ahp[2], ahp[3]});
                const short8 Ad = __builtin_bit_cast(short8, U128{adp[0], adp[1], adp[2], adp[3]});

                floatx4 Dh0 = __builtin_amdgcn_mfma_f32_16x16x32_bf16(Ah, Blo[0], cinit0, 0, 0, 0);
                Dh0         = __builtin_amdgcn_mfma_f32_16x16x32_bf16(Ah, Bhi[0], Dh0,   0, 0, 0);
                floatx4 Dh1 = __builtin_amdgcn_mfma_f32_16x16x32_bf16(Ah, Blo[1], cinit1, 0, 0, 0);
                Dh1         = __builtin_amdgcn_mfma_f32_16x16x32_bf16(Ah, Bhi[1], Dh1,   0, 0, 0);
                floatx4 Dd0 = __builtin_amdgcn_mfma_f32_16x16x32_bf16(Ad, Blo[0], zero,  0, 0, 0);
                Dd0         = __builtin_amdgcn_mfma_f32_16x16x32_bf16(Ad, Bhi[0], Dd0,   0, 0, 0);
                floatx4 Dd1 = __builtin_amdgcn_mfma_f32_16x16x32_bf16(Ad, Blo[1], zero,  0, 0, 0);
                Dd1         = __builtin_amdgcn_mfma_f32_16x16x32_bf16(Ad, Bhi[1], Dd1,   0, 0, 0);

                // ---- D-processing (Dh is tanh-ready: s*preact2) ----
                float va[4], vd[4];
#pragma unroll
                for (int r = 0; r < 4; ++r) {
                    const float h2a = tanh_s(Dh0[r]);
                    const float h2b = tanh_s(Dh1[r]);
                    va[r] = fmaf(h2b, w3n[1], h2a * w3n[0]);
                    const float dda = fmaf(-h2a, h2a, 1.0f) * Dd0[r];
                    const float ddb = fmaf(-h2b, h2b, 1.0f) * Dd1[r];
                    vd[r] = fmaf(ddb, w3q[1], dda * w3q[0]);
                }

                // ---- merged reduction; result indexed by lane&3 == r_o ----
                const float fz = reduce4(va[0], va[1], va[2], va[3], mo, mt);
                const float fl = reduce4(vd[0], vd[1], vd[2], vd[3], mo, mt);
                selx = bsel[b] ? fz : selx;
                sely = bsel[b] ? fl : sely;
            }
            kz = selx + b3v;
            accz = fmaf(w, kz, accz);
            accl = fmaf(w, sely, accl);
        }
        z += accz;
        dlog += accl;
    }

    if (sg < B) {
        out[sg] = z;
        out[(size_t)B + sg] = dlog;
    }
}

extern "C" void kernel_launch(void* const* d_in, const int* in_sizes, int n_in,
                              void* d_out, int out_size, void* d_ws, size_t ws_size,
                              hipStream_t stream) {
    const float* T    = (const float*)d_in[0];
    const float* cond = (const float*)d_in[1];
    const float* W1   = (const float*)d_in[2];
    const float* b1   = (const float*)d_in[3];
    const float* W2   = (const float*)d_in[4];
    const float* b2   = (const float*)d_in[5];
    const float* W3   = (const float*)d_in[6];
    const float* b3   = (const float*)d_in[7];
    float* out = (float*)d_out;

    const int B = in_sizes[0];
    const int grid = (B + 255) / 256;
    cnf_mfma<<<grid, 256, 0, stream>>>(T, cond, W1, b1, W2, b2, W3, b3, out, B);
}

// Round 5
// 981.900 us; speedup vs baseline: 3.1919x; 1.0775x over previous
//
#include <hip/hip_runtime.h>

// ConditionalCNF via MFMA (round 5): round-4 verified structure + packed-fp32
// arithmetic expressed as native float2 vector ops (compiler lowers v2f32
// fadd/fmul/fma to v_pk_add_f32/v_pk_mul_f32/v_pk_fma_f32 on gfx950; falls
// back to scalar with identical semantics).  No inline asm (round-3 NaN).
// d-path bf16 pack by truncation (1 v_perm, no rounding adds).
//
// Verified layouts (rounds 2+4 passed, absmax 0.0156):
//   A-frag:  A[m=lane&15][k=(lane>>4)*8+j]
//   B-frag:  B[k=(lane>>4)*8+j][n=lane&15]
//   C/D:     col=lane&15 (unit), row=(lane>>4)*4+reg (sample-within-block)
//   owner lane o: sample 16*((o>>2)&3) + 4*(o>>4) + (o&3)
//
// Scaling (s = 2*log2 e): W1z, c1, W2, b2 pre-scaled by s so every tanh is
// exp2 -> +1 -> rcp -> fma.  d-path carries s^2, compensated via w3/s^2.

typedef __attribute__((ext_vector_type(8))) short short8;
typedef __attribute__((ext_vector_type(4))) float floatx4;
typedef __attribute__((ext_vector_type(2))) float float2v;

constexpr int NSTEPS = 20;
constexpr float SCL = 2.8853900817779268f;   // 2*log2(e)

struct U128 { unsigned a, b, c, d; };

__device__ __forceinline__ float fexp2(float x) {
#if __has_builtin(__builtin_amdgcn_exp2f)
    return __builtin_amdgcn_exp2f(x);
#else
    return exp2f(x);
#endif
}

__device__ __forceinline__ float2v vfma(float2v a, float2v b, float2v c) {
#if __has_builtin(__builtin_elementwise_fma)
    return __builtin_elementwise_fma(a, b, c);
#else
    float2v d; d.x = fmaf(a.x, b.x, c.x); d.y = fmaf(a.y, b.y, c.y); return d;
#endif
}

// packed tanh with pre-scaled inputs xs = 2*log2(e)*x: tanh = 1 - 2/(exp2+1)
__device__ __forceinline__ float2v tanh_pk(float2v xs) {
    float2v e = {fexp2(xs.x), fexp2(xs.y)};
    float2v ep = e + float2v{1.0f, 1.0f};
    float2v r = {__builtin_amdgcn_rcpf(ep.x), __builtin_amdgcn_rcpf(ep.y)};
    return vfma(r, float2v{-2.0f, -2.0f}, float2v{1.0f, 1.0f});
}

// pack two f32 -> bf16x2, round-half-up (+0x8000, take high halves via v_perm)
__device__ __forceinline__ unsigned pack2bf(float a, float b) {
    unsigned ua = __builtin_bit_cast(unsigned, a) + 0x8000u;
    unsigned ub = __builtin_bit_cast(unsigned, b) + 0x8000u;
    return __builtin_amdgcn_perm(ub, ua, 0x07060302u);   // lo16=bf16(a), hi16=bf16(b)
}
// truncating pack (1 v_perm) — used on the d-path (no ODE feedback; bias ~2^-10)
__device__ __forceinline__ unsigned pack2bf_trunc(float2v v) {
    return __builtin_amdgcn_perm(__builtin_bit_cast(unsigned, v.y),
                                 __builtin_bit_cast(unsigned, v.x), 0x07060302u);
}
__device__ __forceinline__ float bf2f(unsigned bf) {
    return __builtin_bit_cast(float, bf << 16);
}

template <int CTRL>
__device__ __forceinline__ float dpp_radd(float x) {
    int y = __builtin_amdgcn_update_dpp(0, __builtin_bit_cast(int, x), CTRL, 0xf, 0xf, true);
    return x + __builtin_bit_cast(float, y);
}
template <int PAT>
__device__ __forceinline__ float swz_add(float x) {
    int y = __builtin_amdgcn_ds_swizzle(__builtin_bit_cast(int, x), PAT);
    return x + __builtin_bit_cast(float, y);
}

// Sum 4 independent values across each 16-lane row; lane ends holding the full
// row-sum of value index (lane&3).  mo=(lane&1), mt=(lane&2).
__device__ __forceinline__ float reduce4(float v0, float v1, float v2, float v3,
                                         bool mo, bool mt) {
    v0 = dpp_radd<0xB1>(v0);            // + xor1
    v1 = dpp_radd<0xB1>(v1);
    v2 = dpp_radd<0xB1>(v2);
    v3 = dpp_radd<0xB1>(v3);
    float a01 = mo ? v1 : v0;
    float a23 = mo ? v3 : v2;
    a01 = dpp_radd<0x4E>(a01);          // + xor2
    a23 = dpp_radd<0x4E>(a23);
    float a = mt ? a23 : a01;
    a = swz_add<0x101F>(a);             // + xor4
    a = swz_add<0x201F>(a);             // + xor8
    return a;
}

__global__ __launch_bounds__(256) void cnf_mfma(
    const float* __restrict__ Tin, const float* __restrict__ cond,
    const float* __restrict__ W1, const float* __restrict__ b1,
    const float* __restrict__ W2, const float* __restrict__ b2,
    const float* __restrict__ W3, const float* __restrict__ b3,
    float* __restrict__ out, int B)
{
    const int tid   = threadIdx.x;
    const int lane  = tid & 63;
    const int wbase = blockIdx.x * 256 + (tid >> 6) * 64;

    const int m   = lane & 15;
    const int qk  = lane >> 4;
    const int b_o = (lane >> 2) & 3;
    const int r_o = lane & 3;
    const int s_own = 16 * b_o + 4 * qk + r_o;

    const bool mo = (lane & 1) != 0;
    const bool mt = (lane & 2) != 0;
    bool bsel[4];
#pragma unroll
    for (int b = 0; b < 4; ++b) bsel[b] = (b_o == b);

    int addrA[4];
#pragma unroll
    for (int b = 0; b < 4; ++b) addrA[b] = ((m >> 2) * 16 + b * 4 + (m & 3)) * 4;

    // ---- B fragments: s*W2, hi/lo bf16 split; per-lane column constants ----
    short8 Bhi[2], Blo[2];
    float2v w3pv[2], w3qv[2];
    float cb2[2];
    const float is2 = 1.0f / (SCL * SCL);
#pragma unroll
    for (int t = 0; t < 2; ++t) {
        const int u = m + 16 * t;
        const float* w2r = W2 + u * 32 + qk * 8;
        unsigned hu[4], lu[4];
#pragma unroll
        for (int p = 0; p < 4; ++p) {
            const float w0 = SCL * w2r[2 * p], w1v = SCL * w2r[2 * p + 1];
            const unsigned h0 = (__builtin_bit_cast(unsigned, w0) + 0x8000u) >> 16;
            const unsigned h1 = (__builtin_bit_cast(unsigned, w1v) + 0x8000u) >> 16;
            hu[p] = h0 | (h1 << 16);
            lu[p] = pack2bf(w0 - bf2f(h0), w1v - bf2f(h1));
        }
        Bhi[t] = __builtin_bit_cast(short8, U128{hu[0], hu[1], hu[2], hu[3]});
        Blo[t] = __builtin_bit_cast(short8, U128{lu[0], lu[1], lu[2], lu[3]});
        const float w3v = W3[u];
        w3pv[t] = float2v{w3v, w3v};
        w3qv[t] = float2v{w3v * is2, w3v * is2};
        cb2[t] = SCL * b2[u];
    }

    // ---- layer-1 constants for this lane's k-chunk (pre-scaled by s) ----
    float2v w1z2[4];
#pragma unroll
    for (int p = 0; p < 4; ++p)
        w1z2[p] = float2v{SCL * W1[(qk * 8 + 2 * p) * 9],
                          SCL * W1[(qk * 8 + 2 * p + 1) * 9]};

    float2v c12[4][4];
#pragma unroll
    for (int b = 0; b < 4; ++b) {
        int s = wbase + 16 * b + m;
        if (s > B - 1) s = B - 1;
        const float4* c4 = reinterpret_cast<const float4*>(cond + (size_t)s * 8);
        const float4 ca = c4[0], cb = c4[1];
        const float cd[8] = {ca.x, ca.y, ca.z, ca.w, cb.x, cb.y, cb.z, cb.w};
        float c1[8];
#pragma unroll
        for (int j = 0; j < 8; ++j) {
            const int k = qk * 8 + j;
            float acc = b1[k];
#pragma unroll
            for (int jj = 0; jj < 8; ++jj) acc = fmaf(cd[jj], W1[k * 9 + 1 + jj], acc);
            c1[j] = SCL * acc;
        }
#pragma unroll
        for (int p = 0; p < 4; ++p) c12[b][p] = float2v{c1[2 * p], c1[2 * p + 1]};
    }

    const floatx4 cinit0 = {cb2[0], cb2[0], cb2[0], cb2[0]};
    const floatx4 cinit1 = {cb2[1], cb2[1], cb2[1], cb2[1]};
    const floatx4 zero   = {0.0f, 0.0f, 0.0f, 0.0f};

    const float b3v = b3[0];
    const int sg = wbase + s_own;
    float z = Tin[sg < B ? sg : B - 1];
    float dlog = 0.0f;
    const float dt = 1.0f / (float)NSTEPS;

    for (int step = 0; step < NSTEPS; ++step) {
        float kz = 0.0f, accz = 0.0f, accl = 0.0f;
#pragma unroll 1
        for (int s4 = 0; s4 < 4; ++s4) {
            const float a = (s4 == 0) ? 0.0f : ((s4 == 3) ? dt : 0.5f * dt);
            const float w = ((s4 == 0) | (s4 == 3)) ? (dt * (1.0f / 6.0f))
                                                    : (dt * (1.0f / 3.0f));
            const int zi = __builtin_bit_cast(int, fmaf(a, kz, z));
            float selx = 0.0f, sely = 0.0f;

#pragma unroll
            for (int b = 0; b < 4; ++b) {
                const float zin = __builtin_bit_cast(
                    float, __builtin_amdgcn_ds_bpermute(addrA[b], zi));
                const float2v zz = {zin, zin};

                // ---- A-prep: h1 (bf16, rounded) and s*d1 (bf16, truncated) ----
                unsigned ahp[4], adp[4];
#pragma unroll
                for (int p = 0; p < 4; ++p) {
                    const float2v xs = vfma(zz, w1z2[p], c12[b][p]);  // s*preact1
                    const float2v h  = tanh_pk(xs);
                    ahp[p] = pack2bf(h.x, h.y);
                    const float2v u  = h * h;
                    const float2v d  = vfma(u, -w1z2[p], w1z2[p]);    // (1-h^2)*s*w1z
                    adp[p] = pack2bf_trunc(d);
                }
                const short8 Ah = __builtin_bit_cast(short8, U128{ahp[0], ahp[1], ahp[2], ahp[3]});
                const short8 Ad = __builtin_bit_cast(short8, U128{adp[0], adp[1], adp[2], adp[3]});

                floatx4 Dh0 = __builtin_amdgcn_mfma_f32_16x16x32_bf16(Ah, Blo[0], cinit0, 0, 0, 0);
                Dh0         = __builtin_amdgcn_mfma_f32_16x16x32_bf16(Ah, Bhi[0], Dh0,   0, 0, 0);
                floatx4 Dh1 = __builtin_amdgcn_mfma_f32_16x16x32_bf16(Ah, Blo[1], cinit1, 0, 0, 0);
                Dh1         = __builtin_amdgcn_mfma_f32_16x16x32_bf16(Ah, Bhi[1], Dh1,   0, 0, 0);
                floatx4 Dd0 = __builtin_amdgcn_mfma_f32_16x16x32_bf16(Ad, Blo[0], zero,  0, 0, 0);
                Dd0         = __builtin_amdgcn_mfma_f32_16x16x32_bf16(Ad, Bhi[0], Dd0,   0, 0, 0);
                floatx4 Dd1 = __builtin_amdgcn_mfma_f32_16x16x32_bf16(Ad, Blo[1], zero,  0, 0, 0);
                Dd1         = __builtin_amdgcn_mfma_f32_16x16x32_bf16(Ad, Bhi[1], Dd1,   0, 0, 0);

                // ---- D-processing, packed over adjacent accumulator rows ----
                const float2v Dh0lo = __builtin_shufflevector(Dh0, Dh0, 0, 1);
                const float2v Dh0hi = __builtin_shufflevector(Dh0, Dh0, 2, 3);
                const float2v Dh1lo = __builtin_shufflevector(Dh1, Dh1, 0, 1);
                const float2v Dh1hi = __builtin_shufflevector(Dh1, Dh1, 2, 3);
                const float2v Dd0lo = __builtin_shufflevector(Dd0, Dd0, 0, 1);
                const float2v Dd0hi = __builtin_shufflevector(Dd0, Dd0, 2, 3);
                const float2v Dd1lo = __builtin_shufflevector(Dd1, Dd1, 0, 1);
                const float2v Dd1hi = __builtin_shufflevector(Dd1, Dd1, 2, 3);

                const float2v h2a_lo = tanh_pk(Dh0lo);
                const float2v h2a_hi = tanh_pk(Dh0hi);
                const float2v h2b_lo = tanh_pk(Dh1lo);
                const float2v h2b_hi = tanh_pk(Dh1hi);

                const float2v va_lo = vfma(h2b_lo, w3pv[1], h2a_lo * w3pv[0]);
                const float2v va_hi = vfma(h2b_hi, w3pv[1], h2a_hi * w3pv[0]);

                const float2v ta_lo = Dd0lo * w3qv[0];
                const float2v ta_hi = Dd0hi * w3qv[0];
                const float2v tb_lo = Dd1lo * w3qv[1];
                const float2v tb_hi = Dd1hi * w3qv[1];
                const float2v vd_lo = vfma(h2a_lo * h2a_lo, -ta_lo, ta_lo)
                                    + vfma(h2b_lo * h2b_lo, -tb_lo, tb_lo);
                const float2v vd_hi = vfma(h2a_hi * h2a_hi, -ta_hi, ta_hi)
                                    + vfma(h2b_hi * h2b_hi, -tb_hi, tb_hi);

                // ---- merged reduction; result indexed by lane&3 == r_o ----
                const float fz = reduce4(va_lo.x, va_lo.y, va_hi.x, va_hi.y, mo, mt);
                const float fl = reduce4(vd_lo.x, vd_lo.y, vd_hi.x, vd_hi.y, mo, mt);
                selx = bsel[b] ? fz : selx;
                sely = bsel[b] ? fl : sely;
            }
            kz = selx + b3v;
            accz = fmaf(w, kz, accz);
            accl = fmaf(w, sely, accl);
        }
        z += accz;
        dlog += accl;
    }

    if (sg < B) {
        out[sg] = z;
        out[(size_t)B + sg] = dlog;
    }
}

extern "C" void kernel_launch(void* const* d_in, const int* in_sizes, int n_in,
                              void* d_out, int out_size, void* d_ws, size_t ws_size,
                              hipStream_t stream) {
    const float* T    = (const float*)d_in[0];
    const float* cond = (const float*)d_in[1];
    const float* W1   = (const float*)d_in[2];
    const float* b1   = (const float*)d_in[3];
    const float* W2   = (const float*)d_in[4];
    const float* b2   = (const float*)d_in[5];
    const float* W3   = (const float*)d_in[6];
    const float* b3   = (const float*)d_in[7];
    float* out = (float*)d_out;

    const int B = in_sizes[0];
    const int grid = (B + 255) / 256;
    cnf_mfma<<<grid, 256, 0, stream>>>(T, cond, W1, b1, W2, b2, W3, b3, out, B);
}